// Round 1
// baseline (113.241 us; speedup 1.0000x reference)
//
#include <hip/hip_runtime.h>
#include <hip/hip_bf16.h>

typedef __bf16 bf16;
typedef __attribute__((ext_vector_type(8))) __bf16 bf16x8;
typedef __attribute__((ext_vector_type(4))) float f32x4;
typedef __attribute__((ext_vector_type(4))) int i32x4;

#define CH 192
#define MAT (CH * CH)            // 36864
#define NF 145                   // canonical frequencies of 17x17 grid (conj symmetry)
#define FSTRIDE (2 * MAT)        // Re+Im per freq
#define NELEM (CH * CH * 9)      // 331776
#define XSCALE 9.765625e-4f      // 2^-10, exact; sigma = 1024*(s3/289)^(1/16)
#define W17 0.36959913571644626f // 2*pi/17
#define NGRAM (8 * 19 * 3)       // 456 gram blocks (435 active)

// ---------------------------------------------------------------------------
// sigma = ||G^3(K)||_F^(1/8) via 17x17 spectral sampling (exact Parseval).
// ROUND-6 CHANGES (theory: k_dft transposed reads ~850 MB L2 amplification;
// k_gram 3-phase stage/drain tax):
//  - k_dft: thread owns 8 consecutive p (one o-run, fixed a); kv[8][9] in
//    registers, 5-freq loop register-only, 16-B coalesced stores. Grid
//    8*4*18=576 (redundancy 40x -> 4x).
//  - k_gram: diag quadrants stage FULL K=192 once (stride 200, 1 barrier
//    phase); off-diag kc=96 (stride 104, 2 phases). Same MFMA K-order ->
//    bitwise-identical accumulation. LDS 79872 B -> still 2 blocks/CU.
// Lessons pinned from rounds 1-5:
//  - r4: runtime trip counts spill v[] to scratch (+30 us). Staging FULLY
//    UNROLLED with compile-time v[] indices.
//  - r6: spinner-block fusion of the scale +40 us. k_scale stays separate.
//  - r7: MFMA-based DFT regressed (scattered 8-B stores). VALU DFT + LDS
//    twiddle table.
//  - Strides: must be ==0 mod 8 (16-B aligned b128). 200 dw%32=4, 104
//    dw%32=20 -> both 2-way (free) on frag reads.
// XCD pinning: freq f handled by blocks with blockIdx%8 == f%8.
// ws layout: [0] float s3; [256] bufX bf16 [f][2][a][o]; bufH (~21.4 MB ea).
// ---------------------------------------------------------------------------

// X[f][part][a*CH+o] = DFT_17x17(K[o][a])(w_f) * 2^-10.
// Thread owns p0..p0+7 (8 consecutive o, one a); kv in VGPRs across 5 freqs.
__global__ void k_dft(const float* __restrict__ K, bf16* __restrict__ X,
                      float* __restrict__ s3) {
    __shared__ float twc[17], tws[17];
    int bid = blockIdx.x;                 // 8 * 4 * 18 = 576
    int xcd = bid & 7;
    int r = bid >> 3;
    int g = r / 18, chunk = r % 18;
    int t = threadIdx.x;
    if (bid == 0 && t == 0) *s3 = 0.0f;   // stream-ordered: done before gram C
    if (t < 17) {
        float s, c;
        __sincosf(-W17 * (float)t, &s, &c);
        twc[t] = c; tws[t] = s;
    }
    int p0 = chunk * 2048 + t * 8;        // p = a*CH + o; 8-run stays in one a-row
    int a = p0 / CH, o0 = p0 % CH;
    float kv[8][9];
#pragma unroll
    for (int j = 0; j < 8; ++j) {
        const float* src = K + ((size_t)(o0 + j) * CH + a) * 9;
#pragma unroll
        for (int i = 0; i < 9; ++i) kv[j][i] = src[i];
    }
    __syncthreads();
#pragma unroll
    for (int u = 0; u < 5; ++u) {
        int f = xcd + 8 * (g * 5 + u);    // f % 8 == xcd; m < 20 covers f < 160
        if (f >= NF) continue;            // uniform per block
        int fy, fx;
        if (f < 9) { fy = 0; fx = f; }
        else { int uu = f - 9; fy = 1 + uu / 17; fx = uu % 17; }
        float pyr = twc[fy], pyi = tws[fy];
        float pxr = twc[fx], pxi = tws[fx];
        int fx2 = 2 * fx; if (fx2 >= 17) fx2 -= 17;
        int fy2 = 2 * fy; if (fy2 >= 17) fy2 -= 17;
        float px2r = twc[fx2], px2i = tws[fx2];
        float py2r = twc[fy2], py2i = tws[fy2];
        bf16x8 vr, vi;
#pragma unroll
        for (int j = 0; j < 8; ++j) {
            // row sums s_y = kv[y][0] + kv[y][1]*px + kv[y][2]*px^2  (kv real)
            float s0r = kv[j][0] + kv[j][1] * pxr + kv[j][2] * px2r, s0i = kv[j][1] * pxi + kv[j][2] * px2i;
            float s1r = kv[j][3] + kv[j][4] * pxr + kv[j][5] * px2r, s1i = kv[j][4] * pxi + kv[j][5] * px2i;
            float s2r = kv[j][6] + kv[j][7] * pxr + kv[j][8] * px2r, s2i = kv[j][7] * pxi + kv[j][8] * px2i;
            float ar = s0r + pyr * s1r - pyi * s1i + py2r * s2r - py2i * s2i;
            float ai = s0i + pyr * s1i + pyi * s1r + py2r * s2i + py2i * s2r;
            vr[j] = (bf16)(ar * XSCALE);
            vi[j] = (bf16)(ai * XSCALE);
        }
        size_t base = (size_t)f * FSTRIDE + p0;
        *(i32x4*)(X + base)       = __builtin_bit_cast(i32x4, vr);
        *(i32x4*)(X + base + MAT) = __builtin_bit_cast(i32x4, vi);
    }
}

// One conj-gram round: OUT[m,n] = sum_k conj(X[m,k]) * X[n,k]  (per freq).
// Quadrants q=0:(0,0) q=1:(0,96) q=2:(96,96); WRITE emits (96,0)=conj-T(q=1).
// NORM weights q=1 by 2. Block 256 = 4 waves, wave = 48x48 complex.
#define LDSR 104                 // off-diag phase stride: 96 k + 8 pad (bf16)
#define SLAB (96 * LDSR)         // 9984 elems
#define DLDSR 200                // diag full-K stride: 192 k + 8 pad
#define DSLAB (96 * DLDSR)       // 19200 elems (2 slabs = 76800 B <= 79872)
#define OLDSR 104                // epilogue tile stride: 208 B = 13*16 (b128 rows)

#define COMPUTE_KS(STRIDE, SSIZE, SB2, KO_BASE)                                       \
    {                                                                                 \
        bf16x8 ar[3], ai[3], nai[3], br[3], bi[3];                                    \
        int ko = (KO_BASE) + kq;                                                      \
        _Pragma("unroll")                                                             \
        for (int mt = 0; mt < 3; ++mt) {                                              \
            ar[mt] = *(const bf16x8*)&lds[0 * (SSIZE) + (wr + mt * 16 + ml) * (STRIDE) + ko]; \
            ai[mt] = *(const bf16x8*)&lds[1 * (SSIZE) + (wr + mt * 16 + ml) * (STRIDE) + ko]; \
            br[mt] = *(const bf16x8*)&lds[((SB2) + 0) * (SSIZE) + (wc + mt * 16 + ml) * (STRIDE) + ko]; \
            bi[mt] = *(const bf16x8*)&lds[((SB2) + 1) * (SSIZE) + (wc + mt * 16 + ml) * (STRIDE) + ko]; \
            i32x4 uu = __builtin_bit_cast(i32x4, ai[mt]);                             \
            uu ^= 0x80008000;                                                         \
            nai[mt] = __builtin_bit_cast(bf16x8, uu);                                 \
        }                                                                             \
        _Pragma("unroll")                                                             \
        for (int mt = 0; mt < 3; ++mt)                                                \
            _Pragma("unroll")                                                         \
            for (int nt = 0; nt < 3; ++nt) {                                          \
                cr[mt][nt] = __builtin_amdgcn_mfma_f32_16x16x32_bf16(ar[mt],  br[nt], cr[mt][nt], 0, 0, 0); \
                cr[mt][nt] = __builtin_amdgcn_mfma_f32_16x16x32_bf16(ai[mt],  bi[nt], cr[mt][nt], 0, 0, 0); \
                ci[mt][nt] = __builtin_amdgcn_mfma_f32_16x16x32_bf16(ar[mt],  bi[nt], ci[mt][nt], 0, 0, 0); \
                ci[mt][nt] = __builtin_amdgcn_mfma_f32_16x16x32_bf16(nai[mt], br[nt], ci[mt][nt], 0, 0, 0); \
            }                                                                         \
    }

template <bool WRITE, bool NORM>
__global__ __launch_bounds__(256, 2) void k_gram(const bf16* __restrict__ X,
                                                 bf16* __restrict__ Y,
                                                 float* __restrict__ s3) {
    __shared__ bf16 lds[4 * SLAB];      // 79872 B (diag uses 2*DSLAB = 76800)
    __shared__ float red[4];
    int bid = blockIdx.x;
    int xcd = bid & 7, r = bid >> 3;
    int fi = r / 3, q = r % 3;          // q: 0=(0,0) 1=(0,96) 2=(96,96)
    int f = xcd + 8 * fi;
    if (f >= NF) return;                // uniform; before any barrier
    int row0 = (q == 2) ? 96 : 0;
    int col0 = (q >= 1) ? 96 : 0;
    bool diag = (q != 1);
    const bf16* Xf = X + (size_t)f * FSTRIDE;

    int tid = threadIdx.x;
    int lane = tid & 63, w = tid >> 6;
    int wr = (w >> 1) * 48, wc = (w & 1) * 48;
    int ml = lane & 15, kq = (lane >> 4) * 8;

    f32x4 cr[3][3], ci[3][3];
#pragma unroll
    for (int i = 0; i < 3; ++i)
#pragma unroll
        for (int j = 0; j < 3; ++j) {
            cr[i][j] = f32x4{0.f, 0.f, 0.f, 0.f};
            ci[i][j] = f32x4{0.f, 0.f, 0.f, 0.f};
        }

    if (diag) {
        // ---- single full-K stage: 2 slabs x 96 rows x 192 k, stride 200 ----
        i32x4 v[18];
#pragma unroll
        for (int s = 0; s < 2; ++s) {
            const bf16* src = Xf + (s ? MAT : 0) + (size_t)row0 * CH;
#pragma unroll
            for (int j = 0; j < 9; ++j) {
                int c = j * 256 + tid;          // 2304 chunks of 8 per slab
                int rr = c / 24, cc = c % 24;
                v[s * 9 + j] = *(const i32x4*)(src + rr * CH + cc * 8);
            }
        }
#pragma unroll
        for (int s = 0; s < 2; ++s)
#pragma unroll
            for (int j = 0; j < 9; ++j) {
                int c = j * 256 + tid;
                int rr = c / 24, cc = c % 24;
                *(i32x4*)&lds[s * DSLAB + rr * DLDSR + cc * 8] = v[s * 9 + j];
            }
        __syncthreads();
#pragma unroll
        for (int ks = 0; ks < 192; ks += 32) {
            COMPUTE_KS(DLDSR, DSLAB, 0, ks)     // B-frags from A slabs (diag)
        }
    } else {
        // ---- two phases kc={0,96}: 4 slabs x 96 rows x 96 k, stride 104 ----
#pragma unroll
        for (int ph = 0; ph < 2; ++ph) {
            int kc = ph * 96;
            i32x4 v[18];
#pragma unroll
            for (int j = 0; j < 18; ++j) {      // 4608 chunks across 4 slabs
                int gi = j * 256 + tid;
                int s = gi / 1152, c = gi % 1152;
                int rr = c / 12, cc = c % 12;
                const bf16* src = Xf + ((s & 1) ? MAT : 0)
                                + (size_t)(((s < 2) ? row0 : col0) + rr) * CH + kc;
                v[j] = *(const i32x4*)(src + cc * 8);
            }
            __syncthreads();   // prev phase's frag reads done before overwrite
#pragma unroll
            for (int j = 0; j < 18; ++j) {
                int gi = j * 256 + tid;
                int s = gi / 1152, c = gi % 1152;
                int rr = c / 12, cc = c % 12;
                *(i32x4*)&lds[s * SLAB + rr * LDSR + cc * 8] = v[j];
            }
            __syncthreads();
#pragma unroll
            for (int ks = 0; ks < 96; ks += 32) {
                COMPUTE_KS(LDSR, SLAB, 2, ks)
            }
        }
    }

    if (WRITE) {
        // frag -> LDS tile(s) -> coalesced b128 row stores; q=1 scatters conj
        // into a pre-transposed second tile for the (96,0) quadrant.
        bf16* tileA = lds;
        bf16* tileB = lds + 96 * OLDSR;     // 19968 B each, 39936 <= 79872
        bf16* Yf = Y + (size_t)f * FSTRIDE;
        int lr0 = wr + (lane >> 4) * 4;
        int lc0 = wc + ml;
#pragma unroll
        for (int part = 0; part < 2; ++part) {
            __syncthreads();   // frag LDS reads / prev part's global reads done
#pragma unroll
            for (int mt = 0; mt < 3; ++mt)
#pragma unroll
                for (int nt = 0; nt < 3; ++nt)
#pragma unroll
                    for (int rr = 0; rr < 4; ++rr) {
                        float vv = part ? ci[mt][nt][rr] : cr[mt][nt][rr];
                        int rrow = lr0 + mt * 16 + rr;
                        int ccol = lc0 + nt * 16;
                        tileA[rrow * OLDSR + ccol] = (bf16)vv;
                        if (q == 1)
                            tileB[ccol * OLDSR + rrow] = (bf16)(part ? -vv : vv);
                    }
            __syncthreads();
            bf16* dst = Yf + (part ? MAT : 0) + (size_t)row0 * CH + col0;
            for (int ch = tid; ch < 96 * 12; ch += 256) {
                int rw = ch / 12, cc = ch % 12;
                *(i32x4*)&dst[(size_t)rw * CH + cc * 8] = *(const i32x4*)&tileA[rw * OLDSR + cc * 8];
            }
            if (q == 1) {
                bf16* dst2 = Yf + (part ? MAT : 0) + (size_t)col0 * CH + row0;
                for (int ch = tid; ch < 96 * 12; ch += 256) {
                    int rw = ch / 12, cc = ch % 12;
                    *(i32x4*)&dst2[(size_t)rw * CH + cc * 8] = *(const i32x4*)&tileB[rw * OLDSR + cc * 8];
                }
            }
        }
    }
    if (NORM) {
        float loc = 0.f;
#pragma unroll
        for (int mt = 0; mt < 3; ++mt)
#pragma unroll
            for (int nt = 0; nt < 3; ++nt)
#pragma unroll
                for (int rr = 0; rr < 4; ++rr)
                    loc += cr[mt][nt][rr] * cr[mt][nt][rr] + ci[mt][nt][rr] * ci[mt][nt][rr];
#pragma unroll
        for (int off = 32; off > 0; off >>= 1) loc += __shfl_down(loc, off, 64);
        if (lane == 0) red[w] = loc;
        __syncthreads();
        if (tid == 0) {
            float base = (f == 0) ? 1.0f : 2.0f;    // conj-pair weight over freqs
            float wq = (q == 1) ? 2.0f : 1.0f;      // Hermitian quadrant weight
            atomicAdd(s3, base * wq * (red[0] + red[1] + red[2] + red[3]));
        }
    }
}

// sigma = 1024 * (s3/289)^(1/16);  out = K / sigma
__global__ void k_scale(const float* __restrict__ K, float* __restrict__ out,
                        const float* __restrict__ s3) {
    float sig = 1024.0f * exp2f(log2f((*s3) * (1.0f / 289.0f)) * 0.0625f);
    float inv = 1.0f / sig;
    int i = (blockIdx.x * 256 + threadIdx.x) * 4;   // 324 blocks exact
    f32x4 v = *(const f32x4*)(K + i);
    v *= inv;
    *(f32x4*)(out + i) = v;
}

extern "C" void kernel_launch(void* const* d_in, const int* in_sizes, int n_in,
                              void* d_out, int out_size, void* d_ws, size_t ws_size,
                              hipStream_t stream) {
    const float* K = (const float*)d_in[0];
    float* out = (float*)d_out;
    char* ws = (char*)d_ws;
    float* s3 = (float*)ws;
    bf16* bufX = (bf16*)(ws + 256);
    bf16* bufH = bufX + (size_t)NF * FSTRIDE;

    k_dft<<<8 * 4 * 18, 256, 0, stream>>>(K, bufX, s3);                      // X
    k_gram<true,  false><<<NGRAM, 256, 0, stream>>>(bufX, bufH, nullptr);    // H1
    k_gram<true,  false><<<NGRAM, 256, 0, stream>>>(bufH, bufX, nullptr);    // H2
    k_gram<false, true ><<<NGRAM, 256, 0, stream>>>(bufX, nullptr, s3);      // ||H3||^2
    k_scale<<<NELEM / 1024, 256, 0, stream>>>(K, out, s3);
}